// Round 4
// baseline (219.713 us; speedup 1.0000x reference)
//
#include <hip/hip_runtime.h>
#include <hip/hip_bf16.h>

// AttentionBlock3D: GroupNorm(8,256) -> QKV 1x1 conv -> 8-head attn (n=4096, d=64) -> out proj -> +x
// b=2, c=256, n=4096, inner=512. bf16 MFMA, fp32 accum.
// R4: attn rebuilt on 32x32x16 MFMA; P->PV via cvt_pk + shfl_xor(32) (no LDS roundtrip);
//     fixed-max softmax w/ single final shuffle; 2-wave/64q blocks grid=1024; setprio.

typedef __attribute__((ext_vector_type(8))) short bf8_t;     // 8 bf16
typedef __attribute__((ext_vector_type(4))) float f4_t;      // 16x16 C/D frag
typedef __attribute__((ext_vector_type(16))) float f16v;     // 32x32 C/D frag

#define NTOK 4096
#define GRP_ELEMS (32 * 4096)

__device__ __forceinline__ unsigned short f2bf(float f) {
  union { float f; unsigned int i; } v; v.f = f;
  unsigned int r = v.i + 0x7fffu + ((v.i >> 16) & 1u);   // RNE
  return (unsigned short)(r >> 16);
}

__device__ __forceinline__ unsigned int pkbf(float a, float b) {
  float2 t; t.x = a; t.y = b;
  __hip_bfloat162 h = __float22bfloat162_rn(t);
  union { __hip_bfloat162 h; unsigned int u; } c; c.h = h;
  return c.u;
}

__device__ __forceinline__ void gl_lds16(const unsigned short* g, unsigned short* l) {
  __builtin_amdgcn_global_load_lds((const __attribute__((address_space(1))) void*)g,
                                   (__attribute__((address_space(3))) void*)l, 16, 0, 0);
}

// swizzled 16B LDS read; 128B-stride rows: slot ^= row&7
__device__ __forceinline__ bf8_t ldsw128(const unsigned short* base, int row, int du) {
  return *(const bf8_t*)((const char*)base + (((row << 7) + (du << 4)) ^ ((row & 7) << 4)));
}
// 64B-stride rows: slot ^= (row>>1)&3
__device__ __forceinline__ bf8_t ldsw64(const unsigned short* base, int row, int du) {
  return *(const bf8_t*)((const char*)base + (((row << 6) + (du << 4)) ^ (((row >> 1) & 3) << 4)));
}

#if __has_builtin(__builtin_amdgcn_exp2f)
#define EXP2 __builtin_amdgcn_exp2f
#else
#define EXP2 exp2f
#endif

// ---------------- GroupNorm stats (blocks 0..255) + weight cast (blocks 256..767) ----------------
__global__ __launch_bounds__(256) void gn_stats_castw(const float* __restrict__ x, float* __restrict__ stats,
    const float* __restrict__ wqkv, const float* __restrict__ wout,
    unsigned short* __restrict__ wq, unsigned short* __restrict__ wo) {
  int bid = blockIdx.x;
  if (bid >= 256) {
    int i = (bid - 256) * 256 + threadIdx.x;
    const float* src; unsigned short* dst; int off;
    if (i < 98304) { src = wqkv; dst = wq; off = i; }
    else           { src = wout; dst = wo; off = i - 98304; }
    float4 v = ((const float4*)src)[off];
    union { unsigned short s[4]; uint2 u; } o;
    o.s[0] = f2bf(v.x); o.s[1] = f2bf(v.y); o.s[2] = f2bf(v.z); o.s[3] = f2bf(v.w);
    *(uint2*)(dst + (size_t)off * 4) = o.u;
    return;
  }
  int g = bid & 15, sp = bid >> 4;
  const float4* p = (const float4*)(x + (size_t)g * GRP_ELEMS + (size_t)sp * 8192);
  float s = 0.f, s2 = 0.f;
  for (int i = threadIdx.x; i < 2048; i += 256) {
    float4 v = p[i];
    s  += v.x + v.y + v.z + v.w;
    s2 += v.x * v.x + v.y * v.y + v.z * v.z + v.w * v.w;
  }
  for (int m = 32; m; m >>= 1) { s += __shfl_xor(s, m); s2 += __shfl_xor(s2, m); }
  __shared__ float rs[4][2];
  int wv = threadIdx.x >> 6;
  if ((threadIdx.x & 63) == 0) { rs[wv][0] = s; rs[wv][1] = s2; }
  __syncthreads();
  if (threadIdx.x == 0) {
    float ts = rs[0][0] + rs[1][0] + rs[2][0] + rs[3][0];
    float t2 = rs[0][1] + rs[1][1] + rs[2][1] + rs[3][1];
    atomicAdd(&stats[g], ts);
    atomicAdd(&stats[16 + g], t2);
  }
}

// ---------------- GroupNorm apply + transpose to XN^T[b][n][c] bf16 ----------------
__global__ __launch_bounds__(256) void gn_apply(const float* __restrict__ x,
    const float* __restrict__ gamma, const float* __restrict__ beta,
    const float* __restrict__ stats, unsigned short* __restrict__ xnt) {
  __shared__ float t[64][65];
  int b = blockIdx.z, c0 = blockIdx.y * 64, n0 = blockIdx.x * 64;
  int tr = threadIdx.x >> 2;
  int tc = (threadIdx.x & 3) * 16;
  int c = c0 + tr;
  int g = b * 8 + (c >> 5);
  float mu = stats[g] * (1.f / GRP_ELEMS);
  float var = stats[16 + g] * (1.f / GRP_ELEMS) - mu * mu;
  float rstd = rsqrtf(var + 1e-5f);
  float sc = gamma[c] * rstd;
  float sh = beta[c] - mu * sc;
  const float* xp = x + ((size_t)(b * 256 + c)) * NTOK + n0 + tc;
  for (int q = 0; q < 4; ++q) {
    float4 v = *(const float4*)(xp + q * 4);
    t[tr][tc + q * 4 + 0] = v.x * sc + sh;
    t[tr][tc + q * 4 + 1] = v.y * sc + sh;
    t[tr][tc + q * 4 + 2] = v.z * sc + sh;
    t[tr][tc + q * 4 + 3] = v.w * sc + sh;
  }
  __syncthreads();
  int n = n0 + tr;
  union { unsigned short s[16]; uint4 u[2]; } tmp;
  for (int q = 0; q < 16; ++q) tmp.s[q] = f2bf(t[tc + q][tr]);
  uint4* dst = (uint4*)(xnt + ((size_t)b * NTOK + n) * 256 + c0 + tc);
  dst[0] = tmp.u[0];
  dst[1] = tmp.u[1];
}

// ---------------- QKV GEMM: M=1536 K=256 N=4096, 128x128 tile, BK=32, dbuf gload_lds ----------------
__global__ __launch_bounds__(256) void qkv_gemm(const unsigned short* __restrict__ wq,
    const unsigned short* __restrict__ xnt, const float* __restrict__ bqkv,
    unsigned short* __restrict__ Qg, unsigned short* __restrict__ Kg, unsigned short* __restrict__ Vt) {
  __shared__ unsigned short Al[2][4096];
  __shared__ unsigned short Bl[2][4096];
  int b = blockIdx.z, m0 = blockIdx.y * 128, n0 = blockIdx.x * 128;
  const unsigned short* Ap = wq + (size_t)m0 * 256;
  const unsigned short* Bp = xnt + ((size_t)b * NTOK + n0) * 256;
  int lane = threadIdx.x & 63, wv = threadIdx.x >> 6;
  int lq = lane & 15, hq = lane >> 4;
  int m_off = (wv >> 1) * 64, n_off = (wv & 1) * 64;
  f4_t acc[4][4] = {};
  {
    for (int is = 0; is < 2; ++is) {
      int ck = wv * 128 + is * 64 + lane;
      int r = ck >> 2, cu = ck & 3;
      int csw = (cu ^ ((r >> 1) & 3)) << 3;
      gl_lds16(Ap + (size_t)r * 256 + csw, &Al[0][(wv * 128 + is * 64) * 8]);
      gl_lds16(Bp + (size_t)r * 256 + csw, &Bl[0][(wv * 128 + is * 64) * 8]);
    }
  }
  __syncthreads();
  for (int kt = 0; kt < 8; ++kt) {
    int cb = kt & 1, nb = cb ^ 1;
    if (kt < 7) {
      int k0 = (kt + 1) * 32;
      for (int is = 0; is < 2; ++is) {
        int ck = wv * 128 + is * 64 + lane;
        int r = ck >> 2, cu = ck & 3;
        int csw = (cu ^ ((r >> 1) & 3)) << 3;
        gl_lds16(Ap + (size_t)r * 256 + k0 + csw, &Al[nb][(wv * 128 + is * 64) * 8]);
        gl_lds16(Bp + (size_t)r * 256 + k0 + csw, &Bl[nb][(wv * 128 + is * 64) * 8]);
      }
    }
    const unsigned short* Ac = Al[cb];
    const unsigned short* Bc = Bl[cb];
    bf8_t af[4], bfr[4];
    for (int i = 0; i < 4; ++i) af[i]  = ldsw64(Ac, m_off + i * 16 + lq, hq);
    for (int j = 0; j < 4; ++j) bfr[j] = ldsw64(Bc, n_off + j * 16 + lq, hq);
    for (int i = 0; i < 4; ++i)
      for (int j = 0; j < 4; ++j)
        acc[i][j] = __builtin_amdgcn_mfma_f32_16x16x32_bf16(af[i], bfr[j], acc[i][j], 0, 0, 0);
    __syncthreads();
  }
  int tq = m0 >> 9;   // block-uniform: 0=Q,1=K,2=V
  if (tq < 2) {
    unsigned short* dst = tq == 0 ? Qg : Kg;
    float sc = tq == 0 ? 0.1803368801111243f : 1.0f;  // 1/8 * log2(e) folded for exp2 softmax
    for (int i = 0; i < 4; ++i)
      for (int j = 0; j < 4; ++j) {
        int o0 = m0 + m_off + i * 16 + hq * 4;
        int n = n0 + n_off + j * 16 + lq;
        int h = (o0 >> 6) & 7, dd0 = o0 & 63;
        size_t bh = (size_t)b * 8 + h;
        uint2 pk;
        pk.x = pkbf((acc[i][j][0] + bqkv[o0 + 0]) * sc, (acc[i][j][1] + bqkv[o0 + 1]) * sc);
        pk.y = pkbf((acc[i][j][2] + bqkv[o0 + 2]) * sc, (acc[i][j][3] + bqkv[o0 + 3]) * sc);
        *(uint2*)(dst + (bh * NTOK + n) * 64 + dd0) = pk;
      }
  } else {
    for (int i = 0; i < 4; ++i)
      for (int j = 0; j < 4; ++j) {
        int n = n0 + n_off + j * 16 + lq;
        for (int jj = 0; jj < 4; ++jj) {
          int o = m0 + m_off + i * 16 + hq * 4 + jj;
          int h = (o >> 6) & 7, dd = o & 63;
          size_t bh = (size_t)b * 8 + h;
          Vt[(bh * 64 + dd) * NTOK + n] = f2bf(acc[i][j][jj] + bqkv[o]);  // V^T [d][n]
        }
      }
  }
}

// ---------------- Flash attention: 32x32x16 MFMA, grid 1024 x 128thr, 64q/block, 32q/wave ----------------
__global__ __launch_bounds__(128) void attn(const unsigned short* __restrict__ Qg,
    const unsigned short* __restrict__ Kg, const unsigned short* __restrict__ Vt,
    unsigned short* __restrict__ att) {
  __shared__ unsigned short Kls[2][4096];   // 64 kv x 64 d, swizzled (8KB/buf)
  __shared__ unsigned short Vls[2][4096];   // 64 d  x 64 kv, swizzled
  int bid = blockIdx.x;
  // bid = hi*512 + qi*8 + xcd : each XCD owns 2 heads' K/V (1MB <= L2/XCD)
  int bh = (bid & 7) * 2 + (bid >> 9);
  int q0 = ((bid >> 3) & 63) * 64;
  int b = bh >> 3, h = bh & 7;
  const unsigned short* kp = Kg + (size_t)bh * NTOK * 64;
  const unsigned short* vp = Vt + (size_t)bh * 64 * NTOK;
  int tid = threadIdx.x;
  int lane = tid & 63, wv = tid >> 6;
  int l31 = lane & 31, h5 = lane >> 5;
  // Q as B-frags for 32x32x16: aq[t]: B[k=d=t*16+h5*8+e][col=q=l31]
  const unsigned short* qp = Qg + ((size_t)bh * NTOK + q0 + wv * 32 + l31) * 64;
  bf8_t aq[4];
  for (int t4 = 0; t4 < 4; ++t4)
    aq[t4] = *(const bf8_t*)(qp + t4 * 16 + h5 * 8);
  f16v accO[2] = {};       // O^T[d][q]: d = db*32 + (r&3)+8(r>>2)+4h5, q = l31
  float ls = 0.f;          // per-lane partial denominator for q=l31
  {
    for (int is = 0; is < 4; ++is) {
      int ck = is * 128 + tid;            // 512 chunks x 16B = 8KB
      int r = ck >> 3, cu = ck & 7;
      int csw = (cu ^ (r & 7)) << 3;
      gl_lds16(kp + (size_t)r * 64 + csw, &Kls[0][ck * 8]);
      gl_lds16(vp + (size_t)r * NTOK + csw, &Vls[0][ck * 8]);
    }
  }
  __syncthreads();
  #pragma unroll 2
  for (int t = 0; t < 64; ++t) {
    int cb = t & 1, nb = cb ^ 1;
    if (t < 63) {
      int tn = t + 1;
      for (int is = 0; is < 4; ++is) {
        int ck = is * 128 + tid;
        int r = ck >> 3, cu = ck & 7;
        int csw = (cu ^ (r & 7)) << 3;
        gl_lds16(kp + (size_t)(tn * 64 + r) * 64 + csw, &Kls[nb][ck * 8]);
        gl_lds16(vp + (size_t)r * NTOK + tn * 64 + csw, &Vls[nb][ck * 8]);
      }
    }
    const unsigned short* Kc = Kls[cb];
    const unsigned short* Vc = Vls[cb];
    // S^T[kv][q] = K · Q^T  (base-2 logits; 1/8*log2e folded into Q)
    f16v s[2] = {};
    __builtin_amdgcn_s_setprio(1);
    #pragma unroll
    for (int t4 = 0; t4 < 4; ++t4) {
      bf8_t ak0 = ldsw128(Kc, l31, 2 * t4 + h5);
      bf8_t ak1 = ldsw128(Kc, 32 + l31, 2 * t4 + h5);
      s[0] = __builtin_amdgcn_mfma_f32_32x32x16_bf16(ak0, aq[t4], s[0], 0, 0, 0);
      s[1] = __builtin_amdgcn_mfma_f32_32x32x16_bf16(ak1, aq[t4], s[1], 0, 0, 0);
    }
    __builtin_amdgcn_s_setprio(0);
    // fixed-max softmax: P = exp2(S); per-lane partial denominator
    float rs = 0.f;
    #pragma unroll
    for (int kvb = 0; kvb < 2; ++kvb)
      #pragma unroll
      for (int r = 0; r < 16; ++r) {
        float p = EXP2(s[kvb][r]);
        s[kvb][r] = p;
        rs += p;
      }
    ls += rs;
    // P (D-layout) -> PV B-frags via cvt_pk + half-wave exchange.
    // B-frag t4: element e: kv = 16*t4 + 8*h5 + e = s[t4>>1][reg (e&3)+8*(t4&1)+4*h_t] @ lane (l31)+32*(e>>2)
    bf8_t pb[4];
    #pragma unroll
    for (int t4 = 0; t4 < 4; ++t4) {
      int kvb = t4 >> 1, r0 = (t4 & 1) * 8;
      unsigned int pA0 = pkbf(s[kvb][r0 + 0], s[kvb][r0 + 1]);
      unsigned int pA1 = pkbf(s[kvb][r0 + 2], s[kvb][r0 + 3]);
      unsigned int pB0 = pkbf(s[kvb][r0 + 4], s[kvb][r0 + 5]);
      unsigned int pB1 = pkbf(s[kvb][r0 + 6], s[kvb][r0 + 7]);
      unsigned int send0 = h5 ? pA0 : pB0;
      unsigned int send1 = h5 ? pA1 : pB1;
      unsigned int recv0 = __shfl_xor(send0, 32);
      unsigned int recv1 = __shfl_xor(send1, 32);
      union { unsigned int u[4]; bf8_t v; } pk;
      pk.u[0] = h5 ? recv0 : pA0;   // e0,1
      pk.u[1] = h5 ? recv1 : pA1;   // e2,3
      pk.u[2] = h5 ? pB0 : recv0;   // e4,5
      pk.u[3] = h5 ? pB1 : recv1;   // e6,7
      pb[t4] = pk.v;
    }
    // O^T += V^T · P
    __builtin_amdgcn_s_setprio(1);
    #pragma unroll
    for (int t4 = 0; t4 < 4; ++t4) {
      bf8_t av0 = ldsw128(Vc, l31, 2 * t4 + h5);
      bf8_t av1 = ldsw128(Vc, 32 + l31, 2 * t4 + h5);
      accO[0] = __builtin_amdgcn_mfma_f32_32x32x16_bf16(av0, pb[t4], accO[0], 0, 0, 0);
      accO[1] = __builtin_amdgcn_mfma_f32_32x32x16_bf16(av1, pb[t4], accO[1], 0, 0, 0);
    }
    __builtin_amdgcn_s_setprio(0);
    __syncthreads();   // implicit vmcnt(0): prefetch landed; all waves done with buf[cb]
  }
  // denominator: the two h5 halves hold disjoint kv partials for the same q=l31
  ls += __shfl_xor(ls, 32);
  float inv = 1.0f / ls;
  int q = q0 + wv * 32 + l31;
  unsigned short* op = att + ((size_t)b * NTOK + q) * 512 + h * 64;
  #pragma unroll
  for (int db = 0; db < 2; ++db)
    #pragma unroll
    for (int g = 0; g < 4; ++g) {
      uint2 pk;
      pk.x = pkbf(accO[db][g * 4 + 0] * inv, accO[db][g * 4 + 1] * inv);
      pk.y = pkbf(accO[db][g * 4 + 2] * inv, accO[db][g * 4 + 3] * inv);
      *(uint2*)(op + db * 32 + g * 8 + h5 * 4) = pk;
    }
}

// ---------------- out proj: M=256 K=512 N=4096, 64x128 tile (256 blocks), dbuf gload_lds ----------------
__global__ __launch_bounds__(256) void out_proj(const unsigned short* __restrict__ wo,
    const unsigned short* __restrict__ att, const float* __restrict__ bout,
    const float* __restrict__ x, float* __restrict__ y) {
  __shared__ unsigned short Al[2][2048];   // 64 x 32
  __shared__ unsigned short Bl[2][4096];   // 128 x 32
  int b = blockIdx.z, m0 = blockIdx.y * 64, n0 = blockIdx.x * 128;
  const unsigned short* Ap = wo + (size_t)m0 * 512;
  const unsigned short* Bp = att + ((size_t)b * NTOK + n0) * 512;
  int lane = threadIdx.x & 63, wv = threadIdx.x >> 6;
  int lq = lane & 15, hq = lane >> 4;
  int m_off = (wv >> 1) * 32, n_off = (wv & 1) * 64;
  f4_t acc[2][4] = {};
  {
    int ckA = wv * 64 + lane;
    int rA = ckA >> 2, cuA = ckA & 3;
    gl_lds16(Ap + (size_t)rA * 512 + ((cuA ^ ((rA >> 1) & 3)) << 3), &Al[0][(wv * 64) * 8]);
    for (int is = 0; is < 2; ++is) {
      int ck = wv * 128 + is * 64 + lane;
      int r = ck >> 2, cu = ck & 3;
      gl_lds16(Bp + (size_t)r * 512 + ((cu ^ ((r >> 1) & 3)) << 3), &Bl[0][(wv * 128 + is * 64) * 8]);
    }
  }
  __syncthreads();
  for (int kt = 0; kt < 16; ++kt) {
    int cb = kt & 1, nb = cb ^ 1;
    if (kt < 15) {
      int k0 = (kt + 1) * 32;
      int ckA = wv * 64 + lane;
      int rA = ckA >> 2, cuA = ckA & 3;
      gl_lds16(Ap + (size_t)rA * 512 + k0 + ((cuA ^ ((rA >> 1) & 3)) << 3), &Al[nb][(wv * 64) * 8]);
      for (int is = 0; is < 2; ++is) {
        int ck = wv * 128 + is * 64 + lane;
        int r = ck >> 2, cu = ck & 3;
        gl_lds16(Bp + (size_t)r * 512 + k0 + ((cu ^ ((r >> 1) & 3)) << 3), &Bl[nb][(wv * 128 + is * 64) * 8]);
      }
    }
    const unsigned short* Ac = Al[cb];
    const unsigned short* Bc = Bl[cb];
    bf8_t af[2], bfr[4];
    for (int i = 0; i < 2; ++i) af[i]  = ldsw64(Ac, m_off + i * 16 + lq, hq);
    for (int j = 0; j < 4; ++j) bfr[j] = ldsw64(Bc, n_off + j * 16 + lq, hq);
    for (int i = 0; i < 2; ++i)
      for (int j = 0; j < 4; ++j)
        acc[i][j] = __builtin_amdgcn_mfma_f32_16x16x32_bf16(af[i], bfr[j], acc[i][j], 0, 0, 0);
    __syncthreads();
  }
  for (int i = 0; i < 2; ++i)
    for (int j = 0; j < 4; ++j) {
      int n = n0 + n_off + j * 16 + lq;
      for (int jj = 0; jj < 4; ++jj) {
        int co = m0 + m_off + i * 16 + hq * 4 + jj;
        size_t idx = ((size_t)b * 256 + co) * NTOK + n;
        y[idx] = acc[i][j][jj] + bout[co] + x[idx];
      }
    }
}

extern "C" void kernel_launch(void* const* d_in, const int* in_sizes, int n_in,
                              void* d_out, int out_size, void* d_ws, size_t ws_size,
                              hipStream_t stream) {
  const float* x     = (const float*)d_in[0];
  const float* gamma = (const float*)d_in[1];
  const float* beta  = (const float*)d_in[2];
  const float* wqkv  = (const float*)d_in[3];
  const float* bqkv  = (const float*)d_in[4];
  const float* wout  = (const float*)d_in[5];
  const float* bout  = (const float*)d_in[6];
  float* y = (float*)d_out;

  char* ws = (char*)d_ws;
  float*          stats = (float*)ws;                              // 128 B (pad 256)
  unsigned short* WQ    = (unsigned short*)(ws + 256);             // 786432
  unsigned short* WO    = (unsigned short*)(ws + 786688);          // 262144
  unsigned short* XNT   = (unsigned short*)(ws + 1048832);         // 4194304
  unsigned short* Qg    = (unsigned short*)(ws + 5243136);         // 8388608
  unsigned short* Kg    = (unsigned short*)(ws + 13631744);        // 8388608
  unsigned short* Vt    = (unsigned short*)(ws + 22020352);        // 8388608
  unsigned short* ATT   = (unsigned short*)(ws + 30408960);        // 8388608

  hipMemsetAsync(stats, 0, 128, stream);
  gn_stats_castw<<<768, 256, 0, stream>>>(x, stats, wqkv, wout, WQ, WO);
  gn_apply<<<dim3(64, 4, 2), 256, 0, stream>>>(x, gamma, beta, stats, XNT);
  qkv_gemm<<<dim3(32, 12, 2), 256, 0, stream>>>(WQ, XNT, bqkv, Qg, Kg, Vt);
  attn<<<1024, 128, 0, stream>>>(Qg, Kg, Vt, ATT);
  out_proj<<<dim3(32, 4, 2), 256, 0, stream>>>(WO, ATT, bout, x, y);
}